// Round 9
// baseline (3410.159 us; speedup 1.0000x reference)
//
#include <hip/hip_runtime.h>
#include <hip/hip_bf16.h>

#define HID   100
#define SEQ   480
#define INP   640
#define NCLS  307200
#define G4    400
#define TILE  16
#define NTILE 30
#define RING  4

typedef _Float16 h2t   __attribute__((ext_vector_type(2)));
typedef _Float16 f16x8 __attribute__((ext_vector_type(8)));
typedef float    f32x4 __attribute__((ext_vector_type(4)));

__device__ __forceinline__ float fast_sigmoid(float x) {
    return __builtin_amdgcn_rcpf(1.f + __expf(-x));
}
__device__ __forceinline__ float fast_tanh(float x) {
    return 1.f - 2.f * __builtin_amdgcn_rcpf(__expf(2.f * x) + 1.f);
}
__device__ __forceinline__ int ld_acq(const int* p) {
    return __hip_atomic_load(p, __ATOMIC_ACQUIRE, __HIP_MEMORY_SCOPE_AGENT);
}
__device__ __forceinline__ void st_rel(int* p, int v) {
    __hip_atomic_store(p, v, __ATOMIC_RELEASE, __HIP_MEMORY_SCOPE_AGENT);
}
__device__ __forceinline__ f16x8 zero8() {
    f16x8 v;
    #pragma unroll
    for (int i = 0; i < 8; ++i) v[i] = (_Float16)0.f;
    return v;
}
__device__ __forceinline__ f16x8 cvt8(float4 a, float4 b) {
    f16x8 v;
    v[0] = (_Float16)a.x; v[1] = (_Float16)a.y;
    v[2] = (_Float16)a.z; v[3] = (_Float16)a.w;
    v[4] = (_Float16)b.x; v[5] = (_Float16)b.y;
    v[6] = (_Float16)b.z; v[7] = (_Float16)b.w;
    return v;
}
__device__ __forceinline__ f16x8 cvt4z(float4 a) {
    f16x8 v = zero8();
    v[0] = (_Float16)a.x; v[1] = (_Float16)a.y;
    v[2] = (_Float16)a.z; v[3] = (_Float16)a.w;
    return v;
}

// ---------------------------------------------------------------------------
// stage_kernel: 244 blocks x 256 threads.
//   blocks 0..3   : lstm layer l (serial recurrence, Whh only)
//   blocks 4..243 : proj workers, p = bid-4 -> l = p/60, t = (p%60)>>1,
//                   nh = p&1 (column half)
// Workers compute xp tile [16][400] via MFMA f16 into a 4-slot ring per
// layer (xpflag counts completed halves; lstm waits ==2).
// ---------------------------------------------------------------------------
__global__ __launch_bounds__(256, 1) void stage_kernel(
    const float* __restrict__ xin,    // [480][640] stage input
    const float* __restrict__ Wih0,   // [400][640]
    const float* __restrict__ WihR,   // [3][400][100]
    const float* __restrict__ Whh,    // [4][400][100]
    const float* __restrict__ bih,    // [4][400]
    const float* __restrict__ bhh,    // [4][400]
    float* __restrict__ ring,         // [4][RING][16][400]
    _Float16* __restrict__ hseq16,    // [4][480][104] (cols 100..103 zero)
    int* __restrict__ flags)          // [128]
{
    const int bid = blockIdx.x;
    const int tid = threadIdx.x;
    int* hflag  = flags;        // [4]
    int* rdflag = flags + 4;    // [4]
    int* xpflag = flags + 8;    // [120]

    if (bid >= 4) {
        // ================= proj worker (MFMA, 4 waves) =================
        const int p  = bid - 4;
        const int l  = p / 60;
        const int r6 = p % 60;
        const int t  = r6 >> 1;
        const int nh = r6 & 1;
        const int t0 = t * TILE;
        const int lane = tid & 63;
        const int wid  = tid >> 6;      // 0..3
        const int col  = lane & 15;
        const int kb   = lane >> 4;     // 0..3
        const int tile_lo = nh * 13;
        const int tile_hi = nh ? 25 : 13;

        if (l > 0) {
            while (ld_acq(&hflag[l - 1]) < t0 + TILE) __builtin_amdgcn_s_sleep(8);
        }
        if (t >= RING) {
            while (ld_acq(&rdflag[l]) < t - (RING - 1)) __builtin_amdgcn_s_sleep(8);
        }

        float* slot = ring + ((size_t)l * RING + (t & (RING - 1))) * (TILE * G4);

        if (l == 0) {
            f16x8 af[20];
            const float* arow = xin + (size_t)(t0 + col) * INP;
            #pragma unroll
            for (int ks = 0; ks < 20; ++ks) {
                const float* ap = arow + ks * 32 + kb * 8;
                af[ks] = cvt8(*(const float4*)ap, *(const float4*)(ap + 4));
            }
            for (int tile = tile_lo + wid; tile < tile_hi; tile += 4) {
                const int n = tile * 16 + col;
                const float* brow = Wih0 + (size_t)n * INP;
                const float bn = bih[n] + bhh[n];
                f32x4 acc = {bn, bn, bn, bn};
                #pragma unroll
                for (int ks = 0; ks < 20; ++ks) {
                    const float* bp = brow + ks * 32 + kb * 8;
                    f16x8 bf = cvt8(*(const float4*)bp, *(const float4*)(bp + 4));
                    acc = __builtin_amdgcn_mfma_f32_16x16x32_f16(af[ks], bf, acc, 0, 0, 0);
                }
                const int u = n % 100, g = n / 100;
                #pragma unroll
                for (int r = 0; r < 4; ++r)
                    slot[(size_t)(kb * 4 + r) * G4 + u * 4 + g] = acc[r];
            }
        } else {
            f16x8 af[4];
            const _Float16* arow = hseq16 + ((size_t)(l - 1) * SEQ + t0 + col) * 104;
            af[0] = *(const f16x8*)(arow + kb * 8);
            af[1] = *(const f16x8*)(arow + 32 + kb * 8);
            af[2] = *(const f16x8*)(arow + 64 + kb * 8);
            af[3] = (kb == 0) ? *(const f16x8*)(arow + 96) : zero8();
            for (int tile = tile_lo + wid; tile < tile_hi; tile += 4) {
                const int n = tile * 16 + col;
                const float* brow = WihR + ((size_t)(l - 1) * G4 + n) * HID;
                const float bn = bih[l * G4 + n] + bhh[l * G4 + n];
                f32x4 acc = {bn, bn, bn, bn};
                #pragma unroll
                for (int ks = 0; ks < 3; ++ks) {
                    const float* bp = brow + ks * 32 + kb * 8;
                    f16x8 bf = cvt8(*(const float4*)bp, *(const float4*)(bp + 4));
                    acc = __builtin_amdgcn_mfma_f32_16x16x32_f16(af[ks], bf, acc, 0, 0, 0);
                }
                f16x8 bf3 = (kb == 0) ? cvt4z(*(const float4*)(brow + 96)) : zero8();
                acc = __builtin_amdgcn_mfma_f32_16x16x32_f16(af[3], bf3, acc, 0, 0, 0);
                const int u = n % 100, g = n / 100;
                #pragma unroll
                for (int r = 0; r < 4; ++r)
                    slot[(size_t)(kb * 4 + r) * G4 + u * 4 + g] = acc[r];
            }
        }
        __syncthreads();   // drain stores (compiler emits vmcnt(0))
        if (tid == 0)
            __hip_atomic_fetch_add(&xpflag[l * NTILE + t], 1, __ATOMIC_RELEASE,
                                   __HIP_MEMORY_SCOPE_AGENT);
        return;
    }

    // ============ lstm layer block (256 thr, 4 waves) ============
    // gp = tid>>7: gp0 -> gates i,f (owner), gp1 -> gates g,o.
    // j = tid&127 (unit, active j<100). Each thread: full k=100 dot for
    // its 2 gates (50 h2t VGPRs). One parts exchange + 2 barriers/step.
    __shared__ __align__(16) float xp_lds[TILE * G4];   // 25.6 KB
    __shared__ __align__(16) uint  hf16[17][64];        // h rows, f16x2 packed
    __shared__ __align__(16) float2 parts[104];         // gp1 partial (g,o)

    const int l    = bid;
    const int gp   = tid >> 7;
    const int j    = tid & 127;
    const int lane = tid & 63;
    const bool own = (gp == 0) && (j < 100);

    // ---- weights: 2 gates x 100 k as f16x2 (50 VGPRs) ----
    h2t wv[2][50];
    const int jj = (j < 100) ? j : 99;
    #pragma unroll
    for (int g = 0; g < 2; ++g) {
        const float* row = Whh + ((size_t)(l * G4 + (gp * 2 + g) * 100 + jj)) * HID;
        #pragma unroll
        for (int d = 0; d < 50; ++d) {
            float2 f = *(const float2*)(row + 2 * d);
            wv[g][d] = h2t{(_Float16)f.x, (_Float16)f.y};
        }
    }

    for (int i = tid; i < 17 * 64; i += 256) ((uint*)hf16)[i] = 0u;
    float c = 0.f;
    _Float16* hseq_own = hseq16 + (size_t)l * SEQ * 104;
    __syncthreads();

    for (int t = 0; t < NTILE; ++t) {
        const int t0 = t * TILE;

        // ---- wait xp tile (both halves), copy ring -> LDS ----
        while (ld_acq(&xpflag[l * NTILE + t]) < 2) __builtin_amdgcn_s_sleep(2);
        {
            const float4* src = (const float4*)(ring +
                ((size_t)l * RING + (t & (RING - 1))) * (TILE * G4));
            float4* dst = (float4*)xp_lds;
            for (int i = tid; i < TILE * G4 / 4; i += 256) dst[i] = src[i];
        }
        __syncthreads();
        if (tid == 0) st_rel(&rdflag[l], t + 1);

        // ---- 16 recurrent steps ----
        for (int tt = 0; tt < TILE; ++tt) {
            // distributed h: lane c (c<25) holds uint2 = h[4c..4c+3]
            uint2 hv = *(const uint2*)(&hf16[tt][(lane & 31) << 1]);
            float4 xq = own ? *(const float4*)(xp_lds + tt * G4 + (j << 2))
                            : make_float4(0.f, 0.f, 0.f, 0.f);

            float a0e = 0.f, a0o = 0.f, a1e = 0.f, a1o = 0.f;
            #pragma unroll
            for (int cc = 0; cc < 25; ++cc) {
                uint ue = (uint)__builtin_amdgcn_readlane((int)hv.x, cc);
                uint uo = (uint)__builtin_amdgcn_readlane((int)hv.y, cc);
                h2t he = __builtin_bit_cast(h2t, ue);
                h2t ho = __builtin_bit_cast(h2t, uo);
                a0e = __builtin_amdgcn_fdot2(wv[0][2 * cc],     he, a0e, false);
                a0o = __builtin_amdgcn_fdot2(wv[0][2 * cc + 1], ho, a0o, false);
                a1e = __builtin_amdgcn_fdot2(wv[1][2 * cc],     he, a1e, false);
                a1o = __builtin_amdgcn_fdot2(wv[1][2 * cc + 1], ho, a1o, false);
            }
            if (gp == 1 && j < 100)
                parts[j] = make_float2(a0e + a0o, a1e + a1o);
            __syncthreads();

            if (own) {
                float2 q = parts[j];            // (g, o) partials
                float gi = a0e + a0o + xq.x;
                float gf = a1e + a1o + xq.y;
                float gg = q.x + xq.z;
                float go = q.y + xq.w;
                float si = fast_sigmoid(gi);
                float sf = fast_sigmoid(gf);
                float so = fast_sigmoid(go);
                float tg = fast_tanh(gg);
                c = sf * c + si * tg;
                float h = so * fast_tanh(c);
                ((_Float16*)&hf16[tt + 1][0])[j] = (_Float16)h;
            }
            __syncthreads();
        }

        // ---- flush rows 1..16 -> hseq16[t0..t0+15]; roll row16 -> row0 ----
        for (int i = tid; i < 16 * 52; i += 256) {
            const int rr = i / 52, dd = i % 52;
            ((uint*)hseq_own)[(size_t)(t0 + rr) * 52 + dd] = hf16[rr + 1][dd];
        }
        if (tid < 52) hf16[0][tid] = hf16[16][tid];
        __syncthreads();   // drains global stores (vmcnt(0)) + LDS
        if (tid == 0) st_rel(&hflag[l], t0 + TILE);
    }
}

// ---------------------------------------------------------------------------
// fc_blend: out[c] = dot(h_last, fcW[c]) + fcb[c]; optional (.+blend)*0.5
// ---------------------------------------------------------------------------
__global__ __launch_bounds__(256) void fc_blend(
    const _Float16* __restrict__ hlast,  // [104] padded row
    const float* __restrict__ fcW,       // [NCLS][HID]
    const float* __restrict__ fcb,       // [NCLS]
    const float* __restrict__ blend,     // [NCLS] or nullptr
    float* __restrict__ outp, int do_blend)
{
    __shared__ __align__(16) float h_lds[HID + 4];
    const int tid = threadIdx.x;
    if (tid < 104) h_lds[tid] = (tid < 100) ? (float)hlast[tid] : 0.f;
    __syncthreads();

    const int cidx = blockIdx.x * 256 + tid;
    const float4* wr = reinterpret_cast<const float4*>(fcW + (size_t)cidx * HID);
    float acc = fcb[cidx];
    #pragma unroll
    for (int k = 0; k < 25; ++k) {
        float4 w4 = wr[k];
        float4 h4 = reinterpret_cast<const float4*>(h_lds)[k];
        acc = fmaf(w4.x, h4.x, acc);
        acc = fmaf(w4.y, h4.y, acc);
        acc = fmaf(w4.z, h4.z, acc);
        acc = fmaf(w4.w, h4.w, acc);
    }
    if (do_blend) acc = (acc + blend[cidx]) * 0.5f;
    outp[cidx] = acc;
}

// ---------------------------------------------------------------------------
extern "C" void kernel_launch(void* const* d_in, const int* in_sizes, int n_in,
                              void* d_out, int out_size, void* d_ws, size_t ws_size,
                              hipStream_t stream)
{
    const float* x    = (const float*)d_in[0];
    const float* xn   = (const float*)d_in[1];
    const float* xnn  = (const float*)d_in[2];
    const float* Wih0 = (const float*)d_in[3];  // (3, 400, 640)
    const float* WihR = (const float*)d_in[4];  // (3, 3, 400, 100)
    const float* Whh  = (const float*)d_in[5];  // (3, 4, 400, 100)
    const float* bih  = (const float*)d_in[6];  // (3, 4, 400)
    const float* bhh  = (const float*)d_in[7];  // (3, 4, 400)
    const float* fcW  = (const float*)d_in[8];  // (3, 307200, 100)
    const float* fcb  = (const float*)d_in[9];  // (3, 307200)
    float* outp = (float*)d_out;
    float* ws = (float*)d_ws;

    float*     ring   = ws;                                  // 102400 f32
    _Float16*  hseq16 = (_Float16*)(ws + 102400);            // 199680 f16
    float*     cur    = ws + 102400 + 99840;                 // 307200 f32
    int*       flags  = (int*)(ws + 102400 + 99840 + 307200);// 3*128 ints

    hipMemsetAsync(flags, 0, 3 * 128 * sizeof(int), stream);

    for (int s = 0; s < 3; ++s) {
        const float* stage_in = (s == 0) ? x : cur;

        stage_kernel<<<4 + 240, 256, 0, stream>>>(
            stage_in,
            Wih0 + (size_t)s * G4 * INP,
            WihR + (size_t)s * 3 * G4 * HID,
            Whh  + (size_t)s * 4 * G4 * HID,
            bih  + (size_t)s * 4 * G4,
            bhh  + (size_t)s * 4 * G4,
            ring, hseq16, flags + s * 128);

        const float* blend = (s == 0) ? xn : (s == 1) ? xnn : nullptr;
        float* dst = (s == 2) ? outp : cur;
        fc_blend<<<NCLS / 256, 256, 0, stream>>>(
            hseq16 + ((size_t)3 * SEQ + SEQ - 1) * 104,
            fcW + (size_t)s * NCLS * HID, fcb + (size_t)s * NCLS,
            blend, dst, (s < 2) ? 1 : 0);
    }
}

// Round 10
// 3245.575 us; speedup vs baseline: 1.0507x; 1.0507x over previous
//
#include <hip/hip_runtime.h>
#include <hip/hip_bf16.h>

#define HID   100
#define SEQ   480
#define INP   640
#define NCLS  307200
#define G4    400
#define TILE  16
#define NTILE 30
#define RING  4

typedef float    v2    __attribute__((ext_vector_type(2)));
typedef _Float16 h2t   __attribute__((ext_vector_type(2)));
typedef _Float16 f16x8 __attribute__((ext_vector_type(8)));
typedef float    f32x4 __attribute__((ext_vector_type(4)));

__device__ __forceinline__ v2 fma2(v2 a, v2 b, v2 c) {
    return __builtin_elementwise_fma(a, b, c);
}
__device__ __forceinline__ float fast_sigmoid(float x) {
    return __builtin_amdgcn_rcpf(1.f + __expf(-x));
}
__device__ __forceinline__ float fast_tanh(float x) {
    return 1.f - 2.f * __builtin_amdgcn_rcpf(__expf(2.f * x) + 1.f);
}
__device__ __forceinline__ int ld_acq(const int* p) {
    return __hip_atomic_load(p, __ATOMIC_ACQUIRE, __HIP_MEMORY_SCOPE_AGENT);
}
__device__ __forceinline__ void st_rel(int* p, int v) {
    __hip_atomic_store(p, v, __ATOMIC_RELEASE, __HIP_MEMORY_SCOPE_AGENT);
}
__device__ __forceinline__ f16x8 zero8() {
    f16x8 v;
    #pragma unroll
    for (int i = 0; i < 8; ++i) v[i] = (_Float16)0.f;
    return v;
}
__device__ __forceinline__ f16x8 cvt8(float4 a, float4 b) {
    f16x8 v;
    v[0] = (_Float16)a.x; v[1] = (_Float16)a.y;
    v[2] = (_Float16)a.z; v[3] = (_Float16)a.w;
    v[4] = (_Float16)b.x; v[5] = (_Float16)b.y;
    v[6] = (_Float16)b.z; v[7] = (_Float16)b.w;
    return v;
}
__device__ __forceinline__ f16x8 cvt4z(float4 a) {
    f16x8 v = zero8();
    v[0] = (_Float16)a.x; v[1] = (_Float16)a.y;
    v[2] = (_Float16)a.z; v[3] = (_Float16)a.w;
    return v;
}

// ---------------------------------------------------------------------------
// stage_kernel: 244 blocks x 256 threads.
//   blocks 0..3   : lstm layer l (serial recurrence, Whh only)
//   blocks 4..243 : proj workers, p = bid-4 -> l = p/60, t = (p%60)>>1,
//                   nh = p&1 (column half)
// Workers compute xp tile [16][400] via MFMA f16 into a 4-slot ring per
// layer (xpflag counts completed halves; lstm waits ==2).
// ---------------------------------------------------------------------------
__global__ __launch_bounds__(256, 1) void stage_kernel(
    const float* __restrict__ xin,    // [480][640] stage input
    const float* __restrict__ Wih0,   // [400][640]
    const float* __restrict__ WihR,   // [3][400][100]
    const float* __restrict__ Whh,    // [4][400][100]
    const float* __restrict__ bih,    // [4][400]
    const float* __restrict__ bhh,    // [4][400]
    float* __restrict__ ring,         // [4][RING][16][400]
    _Float16* __restrict__ hseq16,    // [4][480][104] (cols 100..103 zero)
    int* __restrict__ flags)          // [128]
{
    const int bid = blockIdx.x;
    const int tid = threadIdx.x;
    int* hflag  = flags;        // [4]
    int* rdflag = flags + 4;    // [4]
    int* xpflag = flags + 8;    // [120]

    if (bid >= 4) {
        // ================= proj worker (MFMA, 4 waves) =================
        const int p  = bid - 4;
        const int l  = p / 60;
        const int r6 = p % 60;
        const int t  = r6 >> 1;
        const int nh = r6 & 1;
        const int t0 = t * TILE;
        const int lane = tid & 63;
        const int wid  = tid >> 6;      // 0..3
        const int col  = lane & 15;
        const int kb   = lane >> 4;     // 0..3
        const int tile_lo = nh * 13;
        const int tile_hi = nh ? 25 : 13;

        if (l > 0) {
            while (ld_acq(&hflag[l - 1]) < t0 + TILE) __builtin_amdgcn_s_sleep(8);
        }
        if (t >= RING) {
            while (ld_acq(&rdflag[l]) < t - (RING - 1)) __builtin_amdgcn_s_sleep(8);
        }

        float* slot = ring + ((size_t)l * RING + (t & (RING - 1))) * (TILE * G4);

        if (l == 0) {
            f16x8 af[20];
            const float* arow = xin + (size_t)(t0 + col) * INP;
            #pragma unroll
            for (int ks = 0; ks < 20; ++ks) {
                const float* ap = arow + ks * 32 + kb * 8;
                af[ks] = cvt8(*(const float4*)ap, *(const float4*)(ap + 4));
            }
            for (int tile = tile_lo + wid; tile < tile_hi; tile += 4) {
                const int n = tile * 16 + col;
                const float* brow = Wih0 + (size_t)n * INP;
                const float bn = bih[n] + bhh[n];
                f32x4 acc = {bn, bn, bn, bn};
                #pragma unroll
                for (int ks = 0; ks < 20; ++ks) {
                    const float* bp = brow + ks * 32 + kb * 8;
                    f16x8 bf = cvt8(*(const float4*)bp, *(const float4*)(bp + 4));
                    acc = __builtin_amdgcn_mfma_f32_16x16x32_f16(af[ks], bf, acc, 0, 0, 0);
                }
                const int u = n % 100, g = n / 100;
                #pragma unroll
                for (int r = 0; r < 4; ++r)
                    slot[(size_t)(kb * 4 + r) * G4 + u * 4 + g] = acc[r];
            }
        } else {
            f16x8 af[4];
            const _Float16* arow = hseq16 + ((size_t)(l - 1) * SEQ + t0 + col) * 104;
            af[0] = *(const f16x8*)(arow + kb * 8);
            af[1] = *(const f16x8*)(arow + 32 + kb * 8);
            af[2] = *(const f16x8*)(arow + 64 + kb * 8);
            af[3] = (kb == 0) ? *(const f16x8*)(arow + 96) : zero8();
            for (int tile = tile_lo + wid; tile < tile_hi; tile += 4) {
                const int n = tile * 16 + col;
                const float* brow = WihR + ((size_t)(l - 1) * G4 + n) * HID;
                const float bn = bih[l * G4 + n] + bhh[l * G4 + n];
                f32x4 acc = {bn, bn, bn, bn};
                #pragma unroll
                for (int ks = 0; ks < 3; ++ks) {
                    const float* bp = brow + ks * 32 + kb * 8;
                    f16x8 bf = cvt8(*(const float4*)bp, *(const float4*)(bp + 4));
                    acc = __builtin_amdgcn_mfma_f32_16x16x32_f16(af[ks], bf, acc, 0, 0, 0);
                }
                f16x8 bf3 = (kb == 0) ? cvt4z(*(const float4*)(brow + 96)) : zero8();
                acc = __builtin_amdgcn_mfma_f32_16x16x32_f16(af[3], bf3, acc, 0, 0, 0);
                const int u = n % 100, g = n / 100;
                #pragma unroll
                for (int r = 0; r < 4; ++r)
                    slot[(size_t)(kb * 4 + r) * G4 + u * 4 + g] = acc[r];
            }
        }
        __syncthreads();   // drain stores (compiler emits vmcnt(0))
        if (tid == 0)
            __hip_atomic_fetch_add(&xpflag[l * NTILE + t], 1, __ATOMIC_RELEASE,
                                   __HIP_MEMORY_SCOPE_AGENT);
        return;
    }

    // ============ lstm layer block (256 thr, 4 waves) — R2-proven step =====
    // hf = tid>>7 (k-half: [0,52)/[52,100)), j = tid&127 (unit).
    // Thread: 4 gates x 52-k f32 dot (w2[4][26] v2). h broadcast: 13 uniform
    // ds_read_b128 from f32 LDS rows. kh1 writes float4 parts; owner
    // (kh0, j<100) combines + activations. Zero global ops in the step loop.
    __shared__ __align__(16) float xp_lds[TILE * G4];   // 25.6 KB
    __shared__ __align__(16) float hrow[17][128];       // f32 h rows, 8.7 KB
    __shared__ __align__(16) float4 parts[104];         // kh1 partial sums

    const int l  = bid;
    const int hf = tid >> 7;
    const int j  = tid & 127;
    const int kb = hf * 52;
    const bool own = (hf == 0) && (j < 100);

    v2 w2[4][26];
    #pragma unroll
    for (int g = 0; g < 4; ++g)
        #pragma unroll
        for (int cc = 0; cc < 26; ++cc) w2[g][cc] = v2{0.f, 0.f};
    if (j < 100) {
        const int nf4 = hf ? 12 : 13;
        #pragma unroll
        for (int g = 0; g < 4; ++g) {
            const float* row = Whh + ((size_t)(l * G4 + g * 100 + j)) * HID + kb;
            #pragma unroll
            for (int cc = 0; cc < 13; ++cc) {
                if (cc < nf4) {
                    float4 t4 = *(const float4*)(row + 4 * cc);
                    w2[g][2 * cc]     = v2{t4.x, t4.y};
                    w2[g][2 * cc + 1] = v2{t4.z, t4.w};
                }
            }
        }
    }

    for (int i = tid; i < 17 * 128; i += 256) ((float*)hrow)[i] = 0.f;
    float c = 0.f;
    _Float16* hseq_own = hseq16 + (size_t)l * SEQ * 104;
    __syncthreads();

    for (int t = 0; t < NTILE; ++t) {
        const int t0 = t * TILE;

        // ---- wait xp tile (both halves), copy ring -> LDS ----
        while (ld_acq(&xpflag[l * NTILE + t]) < 2) __builtin_amdgcn_s_sleep(2);
        {
            const float4* src = (const float4*)(ring +
                ((size_t)l * RING + (t & (RING - 1))) * (TILE * G4));
            float4* dst = (float4*)xp_lds;
            for (int i = tid; i < TILE * G4 / 4; i += 256) dst[i] = src[i];
        }
        __syncthreads();
        if (tid == 0) st_rel(&rdflag[l], t + 1);

        // ---- 16 recurrent steps ----
        for (int tt = 0; tt < TILE; ++tt) {
            const float4* hp = (const float4*)(&hrow[tt][kb]);  // uniform addr

            v2 a0 = {0.f, 0.f}, a1 = {0.f, 0.f};
            v2 a2 = {0.f, 0.f}, a3 = {0.f, 0.f};
            #pragma unroll
            for (int cc = 0; cc < 13; ++cc) {
                float4 hs = hp[cc];
                v2 lo = v2{hs.x, hs.y};
                v2 hi = v2{hs.z, hs.w};
                a0 = fma2(w2[0][2 * cc], lo, a0);
                a1 = fma2(w2[1][2 * cc], lo, a1);
                a2 = fma2(w2[2][2 * cc], lo, a2);
                a3 = fma2(w2[3][2 * cc], lo, a3);
                a0 = fma2(w2[0][2 * cc + 1], hi, a0);
                a1 = fma2(w2[1][2 * cc + 1], hi, a1);
                a2 = fma2(w2[2][2 * cc + 1], hi, a2);
                a3 = fma2(w2[3][2 * cc + 1], hi, a3);
            }
            if (hf == 1 && j < 100)
                parts[j] = make_float4(a0[0] + a0[1], a1[0] + a1[1],
                                       a2[0] + a2[1], a3[0] + a3[1]);
            __syncthreads();

            if (own) {
                float4 q  = parts[j];
                float4 xq = *(const float4*)(xp_lds + tt * G4 + (j << 2));
                float gi = a0[0] + a0[1] + q.x + xq.x;
                float gf = a1[0] + a1[1] + q.y + xq.y;
                float gg = a2[0] + a2[1] + q.z + xq.z;
                float go = a3[0] + a3[1] + q.w + xq.w;
                float si = fast_sigmoid(gi);
                float sf = fast_sigmoid(gf);
                float so = fast_sigmoid(go);
                float tg = fast_tanh(gg);
                c = sf * c + si * tg;
                float h = so * fast_tanh(c);
                hrow[tt + 1][j] = h;
            }
            __syncthreads();
        }

        // ---- flush rows 1..16 (f32 -> packed f16) -> hseq16; roll row ----
        for (int i = tid; i < 16 * 52; i += 256) {
            const int rr = i / 52, dd = i % 52;
            h2t hx;
            hx[0] = (_Float16)hrow[rr + 1][2 * dd];
            hx[1] = (_Float16)hrow[rr + 1][2 * dd + 1];
            ((uint*)hseq_own)[(size_t)(t0 + rr) * 52 + dd] =
                __builtin_bit_cast(uint, hx);
        }
        if (tid < 128) hrow[0][tid] = hrow[16][tid];
        __syncthreads();   // drains global stores (vmcnt(0)) + LDS
        if (tid == 0) st_rel(&hflag[l], t0 + TILE);
    }
}

// ---------------------------------------------------------------------------
// fc_blend: out[c] = dot(h_last, fcW[c]) + fcb[c]; optional (.+blend)*0.5
// ---------------------------------------------------------------------------
__global__ __launch_bounds__(256) void fc_blend(
    const _Float16* __restrict__ hlast,  // [104] padded row
    const float* __restrict__ fcW,       // [NCLS][HID]
    const float* __restrict__ fcb,       // [NCLS]
    const float* __restrict__ blend,     // [NCLS] or nullptr
    float* __restrict__ outp, int do_blend)
{
    __shared__ __align__(16) float h_lds[HID + 4];
    const int tid = threadIdx.x;
    if (tid < 104) h_lds[tid] = (tid < 100) ? (float)hlast[tid] : 0.f;
    __syncthreads();

    const int cidx = blockIdx.x * 256 + tid;
    const float4* wr = reinterpret_cast<const float4*>(fcW + (size_t)cidx * HID);
    float acc = fcb[cidx];
    #pragma unroll
    for (int k = 0; k < 25; ++k) {
        float4 w4 = wr[k];
        float4 h4 = reinterpret_cast<const float4*>(h_lds)[k];
        acc = fmaf(w4.x, h4.x, acc);
        acc = fmaf(w4.y, h4.y, acc);
        acc = fmaf(w4.z, h4.z, acc);
        acc = fmaf(w4.w, h4.w, acc);
    }
    if (do_blend) acc = (acc + blend[cidx]) * 0.5f;
    outp[cidx] = acc;
}

// ---------------------------------------------------------------------------
extern "C" void kernel_launch(void* const* d_in, const int* in_sizes, int n_in,
                              void* d_out, int out_size, void* d_ws, size_t ws_size,
                              hipStream_t stream)
{
    const float* x    = (const float*)d_in[0];
    const float* xn   = (const float*)d_in[1];
    const float* xnn  = (const float*)d_in[2];
    const float* Wih0 = (const float*)d_in[3];  // (3, 400, 640)
    const float* WihR = (const float*)d_in[4];  // (3, 3, 400, 100)
    const float* Whh  = (const float*)d_in[5];  // (3, 4, 400, 100)
    const float* bih  = (const float*)d_in[6];  // (3, 4, 400)
    const float* bhh  = (const float*)d_in[7];  // (3, 4, 400)
    const float* fcW  = (const float*)d_in[8];  // (3, 307200, 100)
    const float* fcb  = (const float*)d_in[9];  // (3, 307200)
    float* outp = (float*)d_out;
    float* ws = (float*)d_ws;

    float*     ring   = ws;                                  // 102400 f32
    _Float16*  hseq16 = (_Float16*)(ws + 102400);            // 199680 f16
    float*     cur    = ws + 102400 + 99840;                 // 307200 f32
    int*       flags  = (int*)(ws + 102400 + 99840 + 307200);// 3*128 ints

    hipMemsetAsync(flags, 0, 3 * 128 * sizeof(int), stream);

    for (int s = 0; s < 3; ++s) {
        const float* stage_in = (s == 0) ? x : cur;

        stage_kernel<<<4 + 240, 256, 0, stream>>>(
            stage_in,
            Wih0 + (size_t)s * G4 * INP,
            WihR + (size_t)s * 3 * G4 * HID,
            Whh  + (size_t)s * 4 * G4 * HID,
            bih  + (size_t)s * 4 * G4,
            bhh  + (size_t)s * 4 * G4,
            ring, hseq16, flags + s * 128);

        const float* blend = (s == 0) ? xn : (s == 1) ? xnn : nullptr;
        float* dst = (s == 2) ? outp : cur;
        fc_blend<<<NCLS / 256, 256, 0, stream>>>(
            hseq16 + ((size_t)3 * SEQ + SEQ - 1) * 104,
            fcW + (size_t)s * NCLS * HID, fcb + (size_t)s * NCLS,
            blend, dst, (s < 2) ? 1 : 0);
    }
}

// Round 11
// 3149.565 us; speedup vs baseline: 1.0827x; 1.0305x over previous
//
#include <hip/hip_runtime.h>
#include <hip/hip_bf16.h>

#define HID   100
#define SEQ   480
#define INP   640
#define NCLS  307200
#define G4    400
#define TILE  16
#define NTILE 30
#define RING  4

typedef _Float16 h2t   __attribute__((ext_vector_type(2)));
typedef _Float16 f16x8 __attribute__((ext_vector_type(8)));
typedef float    f32x4 __attribute__((ext_vector_type(4)));

__device__ __forceinline__ float fast_sigmoid(float x) {
    return __builtin_amdgcn_rcpf(1.f + __expf(-x));
}
__device__ __forceinline__ float fast_tanh(float x) {
    return 1.f - 2.f * __builtin_amdgcn_rcpf(__expf(2.f * x) + 1.f);
}
__device__ __forceinline__ int ld_acq(const int* p) {
    return __hip_atomic_load(p, __ATOMIC_ACQUIRE, __HIP_MEMORY_SCOPE_AGENT);
}
__device__ __forceinline__ void st_rel(int* p, int v) {
    __hip_atomic_store(p, v, __ATOMIC_RELEASE, __HIP_MEMORY_SCOPE_AGENT);
}
__device__ __forceinline__ f16x8 zero8() {
    f16x8 v;
    #pragma unroll
    for (int i = 0; i < 8; ++i) v[i] = (_Float16)0.f;
    return v;
}
__device__ __forceinline__ f16x8 cvt8(float4 a, float4 b) {
    f16x8 v;
    v[0] = (_Float16)a.x; v[1] = (_Float16)a.y;
    v[2] = (_Float16)a.z; v[3] = (_Float16)a.w;
    v[4] = (_Float16)b.x; v[5] = (_Float16)b.y;
    v[6] = (_Float16)b.z; v[7] = (_Float16)b.w;
    return v;
}
__device__ __forceinline__ f16x8 cvt4z(float4 a) {
    f16x8 v = zero8();
    v[0] = (_Float16)a.x; v[1] = (_Float16)a.y;
    v[2] = (_Float16)a.z; v[3] = (_Float16)a.w;
    return v;
}

// ---------------------------------------------------------------------------
// stage_kernel: 244 blocks.
//   blocks 0..3   : lstm layer l — MFMA recurrence, 512 thr (8 waves)
//   blocks 4..243 : proj workers (256 thr), p = bid-4 -> l = p/60,
//                   t = (p%60)>>1, nh = p&1 (column half)
// NOTE: launched with 512 threads; workers use only tid<256.
// ---------------------------------------------------------------------------
__global__ __launch_bounds__(512, 1) void stage_kernel(
    const float* __restrict__ xin,    // [480][640] stage input
    const float* __restrict__ Wih0,   // [400][640]
    const float* __restrict__ WihR,   // [3][400][100]
    const float* __restrict__ Whh,    // [4][400][100]
    const float* __restrict__ bih,    // [4][400]
    const float* __restrict__ bhh,    // [4][400]
    float* __restrict__ ring,         // [4][RING][16][400]
    _Float16* __restrict__ hseq16,    // [4][480][104] (cols 100..103 zero)
    int* __restrict__ flags)          // [128]
{
    const int bid = blockIdx.x;
    const int tid = threadIdx.x;
    int* hflag  = flags;        // [4]
    int* rdflag = flags + 4;    // [4]
    int* xpflag = flags + 8;    // [120]

    if (bid >= 4) {
        // ================= proj worker (MFMA, 4 active waves) ============
        if (tid >= 256) { // parked waves: just hit the barriers the active
            __syncthreads();
            return;
        }
        const int p  = bid - 4;
        const int l  = p / 60;
        const int r6 = p % 60;
        const int t  = r6 >> 1;
        const int nh = r6 & 1;
        const int t0 = t * TILE;
        const int lane = tid & 63;
        const int wid  = tid >> 6;      // 0..3
        const int col  = lane & 15;
        const int kb   = lane >> 4;     // 0..3
        const int tile_lo = nh * 13;
        const int tile_hi = nh ? 25 : 13;

        if (l > 0) {
            while (ld_acq(&hflag[l - 1]) < t0 + TILE) __builtin_amdgcn_s_sleep(8);
        }
        if (t >= RING) {
            while (ld_acq(&rdflag[l]) < t - (RING - 1)) __builtin_amdgcn_s_sleep(8);
        }

        float* slot = ring + ((size_t)l * RING + (t & (RING - 1))) * (TILE * G4);

        if (l == 0) {
            f16x8 af[20];
            const float* arow = xin + (size_t)(t0 + col) * INP;
            #pragma unroll
            for (int ks = 0; ks < 20; ++ks) {
                const float* ap = arow + ks * 32 + kb * 8;
                af[ks] = cvt8(*(const float4*)ap, *(const float4*)(ap + 4));
            }
            for (int tile = tile_lo + wid; tile < tile_hi; tile += 4) {
                const int n = tile * 16 + col;
                const float* brow = Wih0 + (size_t)n * INP;
                const float bn = bih[n] + bhh[n];
                f32x4 acc = {bn, bn, bn, bn};
                #pragma unroll
                for (int ks = 0; ks < 20; ++ks) {
                    const float* bp = brow + ks * 32 + kb * 8;
                    f16x8 bf = cvt8(*(const float4*)bp, *(const float4*)(bp + 4));
                    acc = __builtin_amdgcn_mfma_f32_16x16x32_f16(af[ks], bf, acc, 0, 0, 0);
                }
                const int u = n % 100, g = n / 100;
                #pragma unroll
                for (int r = 0; r < 4; ++r)
                    slot[(size_t)(kb * 4 + r) * G4 + u * 4 + g] = acc[r];
            }
        } else {
            f16x8 af[4];
            const _Float16* arow = hseq16 + ((size_t)(l - 1) * SEQ + t0 + col) * 104;
            af[0] = *(const f16x8*)(arow + kb * 8);
            af[1] = *(const f16x8*)(arow + 32 + kb * 8);
            af[2] = *(const f16x8*)(arow + 64 + kb * 8);
            af[3] = (kb == 0) ? *(const f16x8*)(arow + 96) : zero8();
            for (int tile = tile_lo + wid; tile < tile_hi; tile += 4) {
                const int n = tile * 16 + col;
                const float* brow = WihR + ((size_t)(l - 1) * G4 + n) * HID;
                const float bn = bih[l * G4 + n] + bhh[l * G4 + n];
                f32x4 acc = {bn, bn, bn, bn};
                #pragma unroll
                for (int ks = 0; ks < 3; ++ks) {
                    const float* bp = brow + ks * 32 + kb * 8;
                    f16x8 bf = cvt8(*(const float4*)bp, *(const float4*)(bp + 4));
                    acc = __builtin_amdgcn_mfma_f32_16x16x32_f16(af[ks], bf, acc, 0, 0, 0);
                }
                f16x8 bf3 = (kb == 0) ? cvt4z(*(const float4*)(brow + 96)) : zero8();
                acc = __builtin_amdgcn_mfma_f32_16x16x32_f16(af[3], bf3, acc, 0, 0, 0);
                const int u = n % 100, g = n / 100;
                #pragma unroll
                for (int r = 0; r < 4; ++r)
                    slot[(size_t)(kb * 4 + r) * G4 + u * 4 + g] = acc[r];
            }
        }
        __syncthreads();   // drain stores (compiler emits vmcnt(0))
        if (tid == 0)
            __hip_atomic_fetch_add(&xpflag[l * NTILE + t], 1, __ATOMIC_RELEASE,
                                   __HIP_MEMORY_SCOPE_AGENT);
        return;
    }

    // ============ lstm layer block: MFMA recurrence (512 thr, 8 waves) =====
    // Wave w owns n-tiles {nt == w mod 8}, nt<25 (<=4 tiles, 64 weight VGPRs).
    // Whh resident as B-fragments (f16). h broadcast via 4 ds_read_b128 of a
    // 128-f16 padded h vector, replicated to all 16 A-rows inside the MFMA.
    // D row 0 (lanes 0..15, reg 0) -> gates[400]; owners (tid<100) do the
    // activation chain. Zero global ops and zero readlanes in the step loop.
    __shared__ __align__(16) float xp_lds[TILE * G4];      // 25.6 KB
    __shared__ __align__(16) _Float16 h16[128];            // current h, padded
    __shared__ __align__(16) float gates[G4];              // step gate sums
    __shared__ __align__(16) _Float16 hist[TILE * 104];    // h history tile

    const int l    = bid;
    const int lane = tid & 63;
    const int wid  = tid >> 6;     // 0..7
    const int col  = lane & 15;
    const int kb4  = lane >> 4;    // 0..3

    // ---- resident weight B-fragments: wfrag[tile][ktile] ----
    f16x8 wfrag[4][4];
    #pragma unroll
    for (int i = 0; i < 4; ++i)
        #pragma unroll
        for (int kt = 0; kt < 4; ++kt) wfrag[i][kt] = zero8();
    #pragma unroll
    for (int i = 0; i < 4; ++i) {
        const int nt = wid + 8 * i;
        if (nt < 25) {
            const int r = nt * 16 + col;                  // gate-row 0..399
            const float* wrow = Whh + ((size_t)(l * G4 + r)) * HID;
            #pragma unroll
            for (int kt = 0; kt < 3; ++kt) {              // k 0..95 full
                const float* kp = wrow + kt * 32 + kb4 * 8;
                wfrag[i][kt] = cvt8(*(const float4*)kp, *(const float4*)(kp + 4));
            }
            if (kb4 == 0)                                  // k 96..99 (+pad)
                wfrag[i][3] = cvt4z(*(const float4*)(wrow + 96));
        }
    }

    for (int i = tid; i < 128; i += 512) h16[i] = (_Float16)0.f;
    for (int i = tid; i < TILE * 104; i += 512) hist[i] = (_Float16)0.f;
    float c = 0.f;
    _Float16* hseq_own = hseq16 + (size_t)l * SEQ * 104;
    __syncthreads();

    for (int t = 0; t < NTILE; ++t) {
        const int t0 = t * TILE;

        // ---- wait xp tile (both worker halves), copy ring -> LDS ----
        while (ld_acq(&xpflag[l * NTILE + t]) < 2) __builtin_amdgcn_s_sleep(2);
        {
            const float4* src = (const float4*)(ring +
                ((size_t)l * RING + (t & (RING - 1))) * (TILE * G4));
            float4* dst = (float4*)xp_lds;
            for (int i = tid; i < TILE * G4 / 4; i += 512) dst[i] = src[i];
        }
        __syncthreads();
        if (tid == 0) st_rel(&rdflag[l], t + 1);

        // ---- 16 recurrent steps ----
        for (int tt = 0; tt < TILE; ++tt) {
            // A fragments: h replicated to all 16 rows (broadcast b128 reads)
            f16x8 afr[4];
            #pragma unroll
            for (int kt = 0; kt < 4; ++kt)
                afr[kt] = *(const f16x8*)(h16 + kt * 32 + kb4 * 8);

            #pragma unroll
            for (int i = 0; i < 4; ++i) {
                const int nt = wid + 8 * i;
                if (nt < 25) {
                    f32x4 d = {0.f, 0.f, 0.f, 0.f};
                    #pragma unroll
                    for (int kt = 0; kt < 4; ++kt)
                        d = __builtin_amdgcn_mfma_f32_16x16x32_f16(
                                afr[kt], wfrag[i][kt], d, 0, 0, 0);
                    if (lane < 16) gates[nt * 16 + lane] = d[0];  // D row 0
                }
            }
            __syncthreads();

            if (tid < 100) {
                const int j = tid;
                float4 xq = *(const float4*)(xp_lds + tt * G4 + (j << 2));
                float gi = gates[j]       + xq.x;
                float gf = gates[100 + j] + xq.y;
                float gg = gates[200 + j] + xq.z;
                float go = gates[300 + j] + xq.w;
                float si = fast_sigmoid(gi);
                float sf = fast_sigmoid(gf);
                float so = fast_sigmoid(go);
                float tg = fast_tanh(gg);
                c = sf * c + si * tg;
                float h = so * fast_tanh(c);
                _Float16 h16v = (_Float16)h;
                h16[j] = h16v;
                hist[tt * 104 + j] = h16v;
            }
            __syncthreads();
        }

        // ---- flush hist -> hseq16[t0..t0+15] (packed uint pairs) ----
        for (int i = tid; i < 16 * 52; i += 512) {
            const int rr = i / 52, dd = i % 52;
            ((uint*)hseq_own)[(size_t)(t0 + rr) * 52 + dd] =
                ((const uint*)hist)[rr * 52 + dd];
        }
        __syncthreads();   // drains global stores (vmcnt(0)) + LDS
        if (tid == 0) st_rel(&hflag[l], t0 + TILE);
    }
}

// ---------------------------------------------------------------------------
// fc_blend: out[c] = dot(h_last, fcW[c]) + fcb[c]; optional (.+blend)*0.5
// ---------------------------------------------------------------------------
__global__ __launch_bounds__(256) void fc_blend(
    const _Float16* __restrict__ hlast,  // [104] padded row
    const float* __restrict__ fcW,       // [NCLS][HID]
    const float* __restrict__ fcb,       // [NCLS]
    const float* __restrict__ blend,     // [NCLS] or nullptr
    float* __restrict__ outp, int do_blend)
{
    __shared__ __align__(16) float h_lds[HID + 4];
    const int tid = threadIdx.x;
    if (tid < 104) h_lds[tid] = (tid < 100) ? (float)hlast[tid] : 0.f;
    __syncthreads();

    const int cidx = blockIdx.x * 256 + tid;
    const float4* wr = reinterpret_cast<const float4*>(fcW + (size_t)cidx * HID);
    float acc = fcb[cidx];
    #pragma unroll
    for (int k = 0; k < 25; ++k) {
        float4 w4 = wr[k];
        float4 h4 = reinterpret_cast<const float4*>(h_lds)[k];
        acc = fmaf(w4.x, h4.x, acc);
        acc = fmaf(w4.y, h4.y, acc);
        acc = fmaf(w4.z, h4.z, acc);
        acc = fmaf(w4.w, h4.w, acc);
    }
    if (do_blend) acc = (acc + blend[cidx]) * 0.5f;
    outp[cidx] = acc;
}

// ---------------------------------------------------------------------------
extern "C" void kernel_launch(void* const* d_in, const int* in_sizes, int n_in,
                              void* d_out, int out_size, void* d_ws, size_t ws_size,
                              hipStream_t stream)
{
    const float* x    = (const float*)d_in[0];
    const float* xn   = (const float*)d_in[1];
    const float* xnn  = (const float*)d_in[2];
    const float* Wih0 = (const float*)d_in[3];  // (3, 400, 640)
    const float* WihR = (const float*)d_in[4];  // (3, 3, 400, 100)
    const float* Whh  = (const float*)d_in[5];  // (3, 4, 400, 100)
    const float* bih  = (const float*)d_in[6];  // (3, 4, 400)
    const float* bhh  = (const float*)d_in[7];  // (3, 4, 400)
    const float* fcW  = (const float*)d_in[8];  // (3, 307200, 100)
    const float* fcb  = (const float*)d_in[9];  // (3, 307200)
    float* outp = (float*)d_out;
    float* ws = (float*)d_ws;

    float*     ring   = ws;                                  // 102400 f32
    _Float16*  hseq16 = (_Float16*)(ws + 102400);            // 199680 f16
    float*     cur    = ws + 102400 + 99840;                 // 307200 f32
    int*       flags  = (int*)(ws + 102400 + 99840 + 307200);// 3*128 ints

    hipMemsetAsync(flags, 0, 3 * 128 * sizeof(int), stream);

    for (int s = 0; s < 3; ++s) {
        const float* stage_in = (s == 0) ? x : cur;

        stage_kernel<<<4 + 240, 512, 0, stream>>>(
            stage_in,
            Wih0 + (size_t)s * G4 * INP,
            WihR + (size_t)s * 3 * G4 * HID,
            Whh  + (size_t)s * 4 * G4 * HID,
            bih  + (size_t)s * 4 * G4,
            bhh  + (size_t)s * 4 * G4,
            ring, hseq16, flags + s * 128);

        const float* blend = (s == 0) ? xn : (s == 1) ? xnn : nullptr;
        float* dst = (s == 2) ? outp : cur;
        fc_blend<<<NCLS / 256, 256, 0, stream>>>(
            hseq16 + ((size_t)3 * SEQ + SEQ - 1) * 104,
            fcW + (size_t)s * NCLS * HID, fcb + (size_t)s * NCLS,
            blend, dst, (s < 2) ? 1 : 0);
    }
}

// Round 12
// 2137.992 us; speedup vs baseline: 1.5950x; 1.4731x over previous
//
#include <hip/hip_runtime.h>
#include <hip/hip_bf16.h>

#define HID   100
#define SEQ   480
#define INP   640
#define NCLS  307200
#define G4    400
#define TILE  16
#define NTILE 30

typedef _Float16 h2t   __attribute__((ext_vector_type(2)));
typedef _Float16 f16x8 __attribute__((ext_vector_type(8)));
typedef float    f32x4 __attribute__((ext_vector_type(4)));

__device__ __forceinline__ float fast_sigmoid(float x) {
    return __builtin_amdgcn_rcpf(1.f + __expf(-x));
}
__device__ __forceinline__ float fast_tanh(float x) {
    return 1.f - 2.f * __builtin_amdgcn_rcpf(__expf(2.f * x) + 1.f);
}
__device__ __forceinline__ int ld_acq(const int* p) {
    return __hip_atomic_load(p, __ATOMIC_ACQUIRE, __HIP_MEMORY_SCOPE_AGENT);
}
__device__ __forceinline__ void st_rel(int* p, int v) {
    __hip_atomic_store(p, v, __ATOMIC_RELEASE, __HIP_MEMORY_SCOPE_AGENT);
}
__device__ __forceinline__ f16x8 zero8() {
    f16x8 v;
    #pragma unroll
    for (int i = 0; i < 8; ++i) v[i] = (_Float16)0.f;
    return v;
}
__device__ __forceinline__ f16x8 cvt8(float4 a, float4 b) {
    f16x8 v;
    v[0] = (_Float16)a.x; v[1] = (_Float16)a.y;
    v[2] = (_Float16)a.z; v[3] = (_Float16)a.w;
    v[4] = (_Float16)b.x; v[5] = (_Float16)b.y;
    v[6] = (_Float16)b.z; v[7] = (_Float16)b.w;
    return v;
}
__device__ __forceinline__ f16x8 cvt4z(float4 a) {
    f16x8 v = zero8();
    v[0] = (_Float16)a.x; v[1] = (_Float16)a.y;
    v[2] = (_Float16)a.z; v[3] = (_Float16)a.w;
    return v;
}

// quad_perm broadcast: every lane gets quad-lane C's value (VALU, no LDS)
#define QB(v, C) __int_as_float(__builtin_amdgcn_mov_dpp( \
    __float_as_int(v), (C), 0xf, 0xf, true))

// ---------------------------------------------------------------------------
// proj0: layer-0 input projection, one block per timestep, PACKED output:
// xpT[t][ (j>>2)*16 + ((j&3)<<2) + g ] for unit j, gate g (bias included).
// ---------------------------------------------------------------------------
__global__ __launch_bounds__(512) void proj0_kernel(
    const float* __restrict__ xin, const float* __restrict__ W,
    const float* __restrict__ bih, const float* __restrict__ bhh,
    float* __restrict__ xpT)
{
    __shared__ __align__(16) float xrow[INP];
    const int t = blockIdx.x;
    const int tid = threadIdx.x;

    for (int i = tid; i < INP / 4; i += 512) {
        reinterpret_cast<float4*>(xrow)[i] =
            reinterpret_cast<const float4*>(xin + (size_t)t * INP)[i];
    }
    __syncthreads();

    if (tid < G4) {
        const float4* wr = reinterpret_cast<const float4*>(W + (size_t)tid * INP);
        float acc = bih[tid] + bhh[tid];
        #pragma unroll 5
        for (int k = 0; k < INP / 4; ++k) {
            float4 w4 = wr[k];
            float4 x4 = reinterpret_cast<const float4*>(xrow)[k];
            acc = fmaf(w4.x, x4.x, acc);
            acc = fmaf(w4.y, x4.y, acc);
            acc = fmaf(w4.z, x4.z, acc);
            acc = fmaf(w4.w, x4.w, acc);
        }
        const int j = tid % 100, g = tid / 100;
        xpT[(size_t)t * G4 + ((j >> 2) << 4) + ((j & 3) << 2) + g] = acc;
    }
}

// ---------------------------------------------------------------------------
// lstm_stage: 4 blocks (one per layer) x 512 thr (8 waves). Fully fused:
// per tile: [wait h-flag] -> load hprev tile -> MFMA xp tile (stream Wih
// from L2) -> 16 serial MFMA steps (gate-packed, quad_perm activation,
// 1 barrier/step) -> flush h tile -> publish flag.
// Gate packing: B column c of n-tile nt = Whh row (c&3)*100 + 4*nt + (c>>2)
// so lanes of one quad hold the 4 gates of one unit.
// ---------------------------------------------------------------------------
__global__ __launch_bounds__(512, 1) void lstm_stage(
    const float* __restrict__ xp0T,   // [480][400] packed, bias included
    const float* __restrict__ WihR,   // [3][400][100]
    const float* __restrict__ Whh,    // [4][400][100]
    const float* __restrict__ bih,    // [4][400]
    const float* __restrict__ bhh,    // [4][400]
    _Float16* __restrict__ hseq16,    // [4][480][104] (cols 100..103 zero)
    int* __restrict__ flags)          // [4]
{
    __shared__ __align__(16) float xp_lds[TILE * G4];     // 25.6 KB
    __shared__ __align__(16) _Float16 hprev[TILE * 104];  // 3.3 KB
    __shared__ __align__(16) _Float16 h16[2][128];        // 512 B
    __shared__ __align__(16) _Float16 hist[TILE * 104];   // 3.3 KB

    const int l    = blockIdx.x;
    const int tid  = threadIdx.x;
    const int lane = tid & 63;
    const int wv   = tid >> 6;     // 0..7
    const int col  = lane & 15;
    const int kb4  = lane >> 4;    // 0..3

    // ---- resident Whh B-fragments (gate-packed) + phase-A bias ----
    f16x8 wfrag[4][4];
    float bias[4];
    int   rrs[4];
    #pragma unroll
    for (int i = 0; i < 4; ++i) {
        bias[i] = 0.f; rrs[i] = 0;
        #pragma unroll
        for (int kt = 0; kt < 4; ++kt) wfrag[i][kt] = zero8();
    }
    #pragma unroll
    for (int i = 0; i < 4; ++i) {
        const int nt = wv + 8 * i;
        if (nt < 25) {
            const int rr = (col & 3) * 100 + 4 * nt + (col >> 2);
            rrs[i] = rr;
            const float* wrow = Whh + ((size_t)(l * G4 + rr)) * HID;
            #pragma unroll
            for (int kt = 0; kt < 3; ++kt) {
                const float* kp = wrow + kt * 32 + kb4 * 8;
                wfrag[i][kt] = cvt8(*(const float4*)kp, *(const float4*)(kp + 4));
            }
            if (kb4 == 0)
                wfrag[i][3] = cvt4z(*(const float4*)(wrow + 96));
            if (l > 0)
                bias[i] = bih[l * G4 + rr] + bhh[l * G4 + rr];
        }
    }

    for (int i = tid; i < 128; i += 512) {
        h16[0][i] = (_Float16)0.f;
        h16[1][i] = (_Float16)0.f;
    }
    for (int i = tid; i < TILE * 104; i += 512) hist[i] = (_Float16)0.f;
    float cst[4] = {0.f, 0.f, 0.f, 0.f};
    int cur = 0;
    _Float16* hseq_own = hseq16 + (size_t)l * SEQ * 104;
    const _Float16* hseq_prev = hseq16 + (size_t)(l - 1) * SEQ * 104;
    __syncthreads();

    for (int t = 0; t < NTILE; ++t) {
        const int t0 = t * TILE;

        if (l == 0) {
            // xp tile comes precomputed from proj0
            const float4* src = (const float4*)(xp0T + (size_t)t0 * G4);
            float4* dst = (float4*)xp_lds;
            for (int i = tid; i < TILE * G4 / 4; i += 512) dst[i] = src[i];
            __syncthreads();
        } else {
            // wait for prev layer's h tile, stage it in LDS
            while (ld_acq(&flags[l - 1]) < t0 + TILE) __builtin_amdgcn_s_sleep(2);
            {
                const uint* src = (const uint*)(hseq_prev + (size_t)t0 * 104);
                uint* dst = (uint*)hprev;
                for (int i = tid; i < TILE * 52; i += 512) dst[i] = src[i];
            }
            __syncthreads();

            // phase A: xp_tile = hprev x WihR^T + bias (MFMA, B streamed)
            f16x8 afA[4];
            #pragma unroll
            for (int kt = 0; kt < 3; ++kt)
                afA[kt] = *(const f16x8*)(hprev + col * 104 + kt * 32 + kb4 * 8);
            afA[3] = (kb4 == 0) ? *(const f16x8*)(hprev + col * 104 + 96)
                                : zero8();
            #pragma unroll
            for (int i = 0; i < 4; ++i) {
                const int nt = wv + 8 * i;
                if (nt < 25) {
                    const float* brow =
                        WihR + ((size_t)((l - 1) * G4 + rrs[i])) * HID;
                    f32x4 d = {bias[i], bias[i], bias[i], bias[i]};
                    #pragma unroll
                    for (int kt = 0; kt < 3; ++kt) {
                        const float* kp = brow + kt * 32 + kb4 * 8;
                        f16x8 bf = cvt8(*(const float4*)kp,
                                        *(const float4*)(kp + 4));
                        d = __builtin_amdgcn_mfma_f32_16x16x32_f16(
                                afA[kt], bf, d, 0, 0, 0);
                    }
                    f16x8 bf3 = (kb4 == 0) ? cvt4z(*(const float4*)(brow + 96))
                                           : zero8();
                    d = __builtin_amdgcn_mfma_f32_16x16x32_f16(
                            afA[3], bf3, d, 0, 0, 0);
                    #pragma unroll
                    for (int r = 0; r < 4; ++r)
                        xp_lds[(size_t)(kb4 * 4 + r) * G4 + nt * 16 + col] = d[r];
                }
            }
            __syncthreads();
        }

        // ---- 16 serial steps, 1 barrier each ----
        for (int tt = 0; tt < TILE; ++tt) {
            f16x8 afr[4];
            #pragma unroll
            for (int kt = 0; kt < 4; ++kt)
                afr[kt] = *(const f16x8*)(&h16[cur][kt * 32 + kb4 * 8]);

            #pragma unroll
            for (int i = 0; i < 4; ++i) {
                const int nt = wv + 8 * i;
                if (nt < 25) {
                    const float xq = xp_lds[tt * G4 + nt * 16 + col];
                    f32x4 d = {xq, xq, xq, xq};
                    #pragma unroll
                    for (int kt = 0; kt < 4; ++kt)
                        d = __builtin_amdgcn_mfma_f32_16x16x32_f16(
                                afr[kt], wfrag[i][kt], d, 0, 0, 0);
                    // quad broadcast of the 4 gates (i,f,g,o in quad lanes)
                    const float gi = QB(d[0], 0x00);
                    const float gf = QB(d[0], 0x55);
                    const float gg = QB(d[0], 0xAA);
                    const float go = QB(d[0], 0xFF);
                    const float si = fast_sigmoid(gi);
                    const float sf = fast_sigmoid(gf);
                    const float so = fast_sigmoid(go);
                    const float tg = fast_tanh(gg);
                    cst[i] = sf * cst[i] + si * tg;
                    const float h = so * fast_tanh(cst[i]);
                    if ((lane & 3) == 0 && lane < 16) {
                        const int u = 4 * nt + (col >> 2);
                        const _Float16 hv = (_Float16)h;
                        h16[cur ^ 1][u] = hv;
                        hist[tt * 104 + u] = hv;
                    }
                }
            }
            cur ^= 1;
            __syncthreads();
        }

        // ---- flush h tile, publish ----
        {
            const uint* src = (const uint*)hist;
            uint* dst = (uint*)(hseq_own + (size_t)t0 * 104);
            for (int i = tid; i < TILE * 52; i += 512) dst[i] = src[i];
        }
        __syncthreads();   // drains global stores (vmcnt(0)) + LDS
        if (tid == 0 && l < 3) st_rel(&flags[l], t0 + TILE);
    }
}

// ---------------------------------------------------------------------------
// fc_blend: out[c] = dot(h_last, fcW[c]) + fcb[c]; optional (.+blend)*0.5
// ---------------------------------------------------------------------------
__global__ __launch_bounds__(256) void fc_blend(
    const _Float16* __restrict__ hlast,  // [104] padded row
    const float* __restrict__ fcW,       // [NCLS][HID]
    const float* __restrict__ fcb,       // [NCLS]
    const float* __restrict__ blend,     // [NCLS] or nullptr
    float* __restrict__ outp, int do_blend)
{
    __shared__ __align__(16) float h_lds[HID + 4];
    const int tid = threadIdx.x;
    if (tid < 104) h_lds[tid] = (tid < 100) ? (float)hlast[tid] : 0.f;
    __syncthreads();

    const int cidx = blockIdx.x * 256 + tid;
    const float4* wr = reinterpret_cast<const float4*>(fcW + (size_t)cidx * HID);
    float acc = fcb[cidx];
    #pragma unroll
    for (int k = 0; k < 25; ++k) {
        float4 w4 = wr[k];
        float4 h4 = reinterpret_cast<const float4*>(h_lds)[k];
        acc = fmaf(w4.x, h4.x, acc);
        acc = fmaf(w4.y, h4.y, acc);
        acc = fmaf(w4.z, h4.z, acc);
        acc = fmaf(w4.w, h4.w, acc);
    }
    if (do_blend) acc = (acc + blend[cidx]) * 0.5f;
    outp[cidx] = acc;
}

// ---------------------------------------------------------------------------
extern "C" void kernel_launch(void* const* d_in, const int* in_sizes, int n_in,
                              void* d_out, int out_size, void* d_ws, size_t ws_size,
                              hipStream_t stream)
{
    const float* x    = (const float*)d_in[0];
    const float* xn   = (const float*)d_in[1];
    const float* xnn  = (const float*)d_in[2];
    const float* Wih0 = (const float*)d_in[3];  // (3, 400, 640)
    const float* WihR = (const float*)d_in[4];  // (3, 3, 400, 100)
    const float* Whh  = (const float*)d_in[5];  // (3, 4, 400, 100)
    const float* bih  = (const float*)d_in[6];  // (3, 4, 400)
    const float* bhh  = (const float*)d_in[7];  // (3, 4, 400)
    const float* fcW  = (const float*)d_in[8];  // (3, 307200, 100)
    const float* fcb  = (const float*)d_in[9];  // (3, 307200)
    float* outp = (float*)d_out;
    float* ws = (float*)d_ws;

    float*     xp0T   = ws;                                  // 192000 f32
    _Float16*  hseq16 = (_Float16*)(ws + 192000);            // 199680 f16
    float*     cur    = ws + 192000 + 99840;                 // 307200 f32
    int*       flags  = (int*)(ws + 192000 + 99840 + 307200);// 12 ints

    hipMemsetAsync(flags, 0, 12 * sizeof(int), stream);

    for (int s = 0; s < 3; ++s) {
        const float* stage_in = (s == 0) ? x : cur;

        proj0_kernel<<<SEQ, 512, 0, stream>>>(
            stage_in, Wih0 + (size_t)s * G4 * INP,
            bih + (size_t)(s * 4) * G4, bhh + (size_t)(s * 4) * G4,
            xp0T);

        lstm_stage<<<4, 512, 0, stream>>>(
            xp0T,
            WihR + (size_t)s * 3 * G4 * HID,
            Whh  + (size_t)s * 4 * G4 * HID,
            bih  + (size_t)s * 4 * G4,
            bhh  + (size_t)s * 4 * G4,
            hseq16, flags + s * 4);

        const float* blend = (s == 0) ? xn : (s == 1) ? xnn : nullptr;
        float* dst = (s == 2) ? outp : cur;
        fc_blend<<<NCLS / 256, 256, 0, stream>>>(
            hseq16 + ((size_t)3 * SEQ + SEQ - 1) * 104,
            fcW + (size_t)s * NCLS * HID, fcb + (size_t)s * NCLS,
            blend, dst, (s < 2) ? 1 : 0);
    }
}